// Round 2
// baseline (463.078 us; speedup 1.0000x reference)
//
#include <hip/hip_runtime.h>

#define NSEQ 2048
#define DMODEL 1024
#define NHEAD 16
#define HDIM 64
#define NBATCH 4
#define MTOT 8192
#define ATT_SCALE 0.125f
#define LOG2E 1.4426950408889634f

typedef __bf16 bf16x8 __attribute__((ext_vector_type(8)));
typedef float f32x4 __attribute__((ext_vector_type(4)));
typedef unsigned short u16;
typedef unsigned int u32;
typedef unsigned long long u64;

__device__ __forceinline__ u16 f2bf(float f) {
  u32 u = __builtin_bit_cast(u32, f);
  return (u16)((u + 0x7fffu + ((u >> 16) & 1u)) >> 16);
}

__device__ __forceinline__ void gload_lds16(const void* g, void* l) {
  __builtin_amdgcn_global_load_lds(
      (__attribute__((address_space(1))) const u32*)g,
      (__attribute__((address_space(3))) u32*)l, 16, 0, 0);
}

// ---------------- cast fp32 -> bf16 ----------------
__global__ __launch_bounds__(256) void cast_f32_bf16(const float* __restrict__ in,
                                                     u16* __restrict__ out, int n) {
  int i = (blockIdx.x * 256 + threadIdx.x) * 4;
  if (i >= n) return;
  float4 v = *(const float4*)(in + i);
  ushort4 o;
  o.x = f2bf(v.x); o.y = f2bf(v.y); o.z = f2bf(v.z); o.w = f2bf(v.w);
  *(ushort4*)(out + i) = o;
}

// ---------------- pack mask int32 -> bit per element ----------------
// mask [4,2048,2048] int32 -> bits [4*2048][32] u64 (bit j of word c = col c*64+j)
__global__ __launch_bounds__(256) void pack_mask(const int* __restrict__ mask,
                                                 u64* __restrict__ bits) {
  int wave = (blockIdx.x * 256 + threadIdx.x) >> 6;
  int lane = threadIdx.x & 63;
  const int* row = mask + (size_t)wave * NSEQ;
  u64* out = bits + (size_t)wave * 32;
  for (int c = 0; c < 32; ++c) {
    int v = row[c * 64 + lane];
    u64 bl = __ballot(v != 0);
    if (lane == 0) out[c] = bl;
  }
}

// ---------------- BT-GEMM: C[m,n] = sum_k A[m,k]*W[n,k] ----------------
template <int MODE>
__global__ __launch_bounds__(256) void gemm_bt(const u16* __restrict__ A,
                                               const u16* __restrict__ W,
                                               void* __restrict__ C) {
  __shared__ __align__(16) u16 Al[128 * 64];
  __shared__ __align__(16) u16 Bl[128 * 64];
  const int tid = threadIdx.x;
  const int w = tid >> 6, l = tid & 63;
  const int l15 = l & 15, l4 = l >> 4;
  const int bm = blockIdx.x, bn = blockIdx.y;
  const int wm = w >> 1, wn = w & 1;

  f32x4 acc[4][4] = {};

  for (int ks = 0; ks < 1024; ks += 64) {
    __syncthreads();
#pragma unroll
    for (int c = 0; c < 4; ++c) {
      int g = w * 256 + c * 64 + l;
      int row = g >> 3, gc = g & 7;
      int sgc = gc ^ (row & 7);
      gload_lds16(A + (size_t)(bm * 128 + row) * 1024 + ks + sgc * 8, &Al[g * 8]);
      gload_lds16(W + (size_t)(bn * 128 + row) * 1024 + ks + sgc * 8, &Bl[g * 8]);
    }
    __syncthreads();
#pragma unroll
    for (int kc = 0; kc < 2; ++kc) {
      bf16x8 af[4], bfr[4];
#pragma unroll
      for (int mi = 0; mi < 4; ++mi) {
        int row = wm * 64 + mi * 16 + l15;
        int gc2 = (kc * 4 + l4) ^ (row & 7);
        af[mi] = *(const bf16x8*)&Al[row * 64 + gc2 * 8];
      }
#pragma unroll
      for (int ni = 0; ni < 4; ++ni) {
        int row = wn * 64 + ni * 16 + l15;
        int gc2 = (kc * 4 + l4) ^ (row & 7);
        bfr[ni] = *(const bf16x8*)&Bl[row * 64 + gc2 * 8];
      }
#pragma unroll
      for (int mi = 0; mi < 4; ++mi)
#pragma unroll
        for (int ni = 0; ni < 4; ++ni)
          acc[mi][ni] = __builtin_amdgcn_mfma_f32_16x16x32_bf16(af[mi], bfr[ni],
                                                                acc[mi][ni], 0, 0, 0);
    }
  }

#pragma unroll
  for (int mi = 0; mi < 4; ++mi)
#pragma unroll
    for (int ni = 0; ni < 4; ++ni)
#pragma unroll
      for (int r = 0; r < 4; ++r) {
        int m = bm * 128 + wm * 64 + mi * 16 + l4 * 4 + r;
        int n = bn * 128 + wn * 64 + ni * 16 + l15;
        float val = acc[mi][ni][r];
        if constexpr (MODE == 0) {
          int b = m >> 11, row = m & 2047, h = n >> 6, d = n & 63;
          ((u16*)C)[(((size_t)(b * 16 + h)) * NSEQ + row) * 64 + d] = f2bf(val);
        } else if constexpr (MODE == 1) {
          ((float*)C)[(size_t)m * 1024 + n] = val;
        } else {
          int b = m >> 11, kk = m & 2047, h = n >> 6, d = n & 63;
          ((u16*)C)[(((size_t)(b * 16 + h)) * 64 + d) * NSEQ + kk] = f2bf(val);
        }
      }
}

// ---------------- flash attention ----------------
// grid 2048 blocks (XCD-remapped), block 256 = 4 waves x 16 q-rows, KT=64,
// double-buffered K/V/alibi staging, packed mask bits, defer-max.
__global__ __launch_bounds__(256) void attn_kernel(
    const u16* __restrict__ q, const u16* __restrict__ k, const u16* __restrict__ vT,
    const float* __restrict__ alibi, const u64* __restrict__ mbits,
    u16* __restrict__ o) {
  __shared__ __align__(16) u16 Pl[4][16 * 64];    // 8 KB
  __shared__ __align__(16) u16 Kl[2][64 * 64];    // 16 KB
  __shared__ __align__(16) u16 Vl[2][64 * 64];    // 16 KB
  __shared__ __align__(16) float Av[2][64 * 64];  // 32 KB

  const int tid = threadIdx.x, w = tid >> 6, l = tid & 63;
  const int l15 = l & 15, l4 = l >> 4;
  // XCD-aware bijective remap (2048 = 8 * 256): same-XCD neighbors share K/V.
  const int W = blockIdx.x + 32 * blockIdx.y;
  const int W2 = (W & 7) * 256 + (W >> 3);
  const int qb = W2 & 31, Y = W2 >> 5;
  const int h = Y >> 2, b = Y & 3, bh = b * 16 + h;
  const int wq0 = qb * 64 + w * 16;

  // Q fragment (A-operand rows = l15)
  bf16x8 aq[2];
  {
    const u16* qrow = q + ((size_t)bh * NSEQ + wq0 + l15) * 64;
    aq[0] = *(const bf16x8*)(qrow + l4 * 8);
    aq[1] = *(const bf16x8*)(qrow + 32 + l4 * 8);
  }

  // persistent staging pointers (advanced by constants each tile)
  const u16* kg[2]; const u16* vg[2]; const float* ag[4];
#pragma unroll
  for (int c = 0; c < 2; ++c) {
    int g = w * 128 + c * 64 + l;
    int row = g >> 3, gc = g & 7, sgc = gc ^ (row & 7);
    kg[c] = k + ((size_t)bh * NSEQ + row) * 64 + sgc * 8;
    vg[c] = vT + ((size_t)bh * 64 + row) * NSEQ + sgc * 8;
  }
#pragma unroll
  for (int c = 0; c < 4; ++c) {
    int G = c * 256 + tid;
    int row = G >> 4, gl = G & 15;
    int sg = gl ^ (((row >> 2) & 3) << 2);
    ag[c] = alibi + (size_t)h * NSEQ * NSEQ + (size_t)(qb * 64 + row) * NSEQ + sg * 4;
  }

  // mask-bit row pointers (advance with t)
  const u64* mp[4];
#pragma unroll
  for (int r = 0; r < 4; ++r)
    mp[r] = mbits + ((size_t)b * NSEQ + wq0 + l4 * 4 + r) * 32;

  // loop-invariant LDS read offsets
  const int kfr[2] = { l15 * 128 + (((0 + l4) ^ (l15 & 7)) << 4),
                       l15 * 128 + (((4 + l4) ^ (l15 & 7)) << 4) };
  int abyte[4];
#pragma unroll
  for (int r = 0; r < 4; ++r)
    abyte[r] = (w * 16 + l4 * 4 + r) * 256 + ((l15 >> 2) << 4) + (l15 & 3) * 4;
  const int kboff[4] = { ((0 ^ l4) & 3) << 6, ((1 ^ l4) & 3) << 6,
                         ((2 ^ l4) & 3) << 6, ((3 ^ l4) & 3) << 6 };
  u16* PW = &Pl[w][0];

  f32x4 oacc[4] = {};
  float m_run[4], l_run[4];
#pragma unroll
  for (int r = 0; r < 4; ++r) { m_run[r] = -3.0e38f; l_run[r] = 0.f; }

  auto stage = [&](u16* KB, u16* VB, float* AB) {
#pragma unroll
    for (int c = 0; c < 2; ++c) {
      gload_lds16(kg[c], (char*)KB + (w * 128 + c * 64 + l) * 16);
      kg[c] += 4096;  // 64 rows * 128 B
      gload_lds16(vg[c], (char*)VB + (w * 128 + c * 64 + l) * 16);
      vg[c] += 64;    // 128 B along k
    }
#pragma unroll
    for (int c = 0; c < 4; ++c) {
      gload_lds16(ag[c], (char*)AB + (c * 256 + tid) * 16);
      ag[c] += 64;    // 256 B along k
    }
  };

  stage(Kl[0], Vl[0], Av[0]);
  __syncthreads();

  auto body = [&](const u16* KB, const u16* VB, const float* AB,
                  u16* KN, u16* VN, float* AN, int t, bool dost) {
    u64 mb[4];
#pragma unroll
    for (int r = 0; r < 4; ++r) mb[r] = mp[r][t];
    if (dost) stage(KN, VN, AN);

    // S = Q K^T
    f32x4 sacc[4];
#pragma unroll
    for (int kb = 0; kb < 4; ++kb) {
      f32x4 z = {0.f, 0.f, 0.f, 0.f};
      sacc[kb] = z;
#pragma unroll
      for (int kc = 0; kc < 2; ++kc) {
        bf16x8 bk = *(const bf16x8*)((const char*)KB + kfr[kc] + kb * 2048);
        sacc[kb] = __builtin_amdgcn_mfma_f32_16x16x32_bf16(aq[kc], bk, sacc[kb], 0, 0, 0);
      }
    }

    // sv = s*scale + alibi (alibi from swizzled LDS, addrs precomputed)
    float sv[4][4];
#pragma unroll
    for (int kb = 0; kb < 4; ++kb)
#pragma unroll
      for (int r = 0; r < 4; ++r) {
        float al = *(const float*)((const char*)AB + abyte[r] + kboff[kb]);
        sv[kb][r] = fmaf(sacc[kb][r], ATT_SCALE, al);
      }

    // mask: wave-uniform fast path when all 64x16 bits set
    bool ok = ((mb[0] & mb[1] & mb[2] & mb[3]) == ~0ull);
    if (!__all(ok)) {
#pragma unroll
      for (int kb = 0; kb < 4; ++kb)
#pragma unroll
        for (int r = 0; r < 4; ++r)
          if (!((mb[r] >> (kb * 16 + l15)) & 1)) sv[kb][r] = -3.0e38f;
    }

    // row max over 16 l15-lanes
    float tm[4];
#pragma unroll
    for (int r = 0; r < 4; ++r)
      tm[r] = fmaxf(fmaxf(sv[0][r], sv[1][r]), fmaxf(sv[2][r], sv[3][r]));
#pragma unroll
    for (int off = 1; off < 16; off <<= 1)
#pragma unroll
      for (int r = 0; r < 4; ++r) tm[r] = fmaxf(tm[r], __shfl_xor(tm[r], off));

    // defer-max: rescale only when some row grows by > 4
    float grow = fmaxf(fmaxf(tm[0] - m_run[0], tm[1] - m_run[1]),
                       fmaxf(tm[2] - m_run[2], tm[3] - m_run[3]));
    if (__any(grow > 4.0f)) {
#pragma unroll
      for (int r = 0; r < 4; ++r) {
        float mn = fmaxf(m_run[r], tm[r]);
        float fac = exp2f((m_run[r] - mn) * LOG2E);
        m_run[r] = mn;
        l_run[r] *= fac;
#pragma unroll
        for (int db = 0; db < 4; ++db) oacc[db][r] *= fac;
      }
    }

    float negmL[4];
#pragma unroll
    for (int r = 0; r < 4; ++r) negmL[r] = -m_run[r] * LOG2E;

    float ts[4] = {0.f, 0.f, 0.f, 0.f};
#pragma unroll
    for (int kb = 0; kb < 4; ++kb)
#pragma unroll
      for (int r = 0; r < 4; ++r) {
        float p = exp2f(fmaf(sv[kb][r], LOG2E, negmL[r]));
        sv[kb][r] = p;
        ts[r] += p;
      }
#pragma unroll
    for (int off = 1; off < 16; off <<= 1)
#pragma unroll
      for (int r = 0; r < 4; ++r) ts[r] += __shfl_xor(ts[r], off);
#pragma unroll
    for (int r = 0; r < 4; ++r) l_run[r] += ts[r];

    // write P (bf16, swizzled) to per-wave LDS
#pragma unroll
    for (int kb = 0; kb < 4; ++kb)
#pragma unroll
      for (int r = 0; r < 4; ++r) {
        int qloc = l4 * 4 + r;
        int gc3 = (kb * 2 + (l15 >> 3)) ^ (qloc & 7);
        *(u16*)((char*)PW + qloc * 128 + gc3 * 16 + (l15 & 7) * 2) = f2bf(sv[kb][r]);
      }
    asm volatile("s_waitcnt lgkmcnt(0)" ::: "memory");
    __builtin_amdgcn_sched_barrier(0);

    // O += P V
#pragma unroll
    for (int kc = 0; kc < 2; ++kc) {
      bf16x8 pa = *(const bf16x8*)((const char*)PW + kfr[kc]);
#pragma unroll
      for (int db = 0; db < 4; ++db) {
        bf16x8 bv = *(const bf16x8*)((const char*)VB + kfr[kc] + db * 2048);
        oacc[db] = __builtin_amdgcn_mfma_f32_16x16x32_bf16(pa, bv, oacc[db], 0, 0, 0);
      }
    }
    __syncthreads();
  };

  for (int t2 = 0; t2 < 16; ++t2) {
    body(Kl[0], Vl[0], Av[0], Kl[1], Vl[1], Av[1], t2 * 2, true);
    body(Kl[1], Vl[1], Av[1], Kl[0], Vl[0], Av[0], t2 * 2 + 1, t2 < 15);
  }

  // normalize + write O into [B, N, 1024] bf16
#pragma unroll
  for (int r = 0; r < 4; ++r) {
    float inv = __builtin_amdgcn_rcpf(l_run[r]);
    int qrow = wq0 + l4 * 4 + r;
#pragma unroll
    for (int db = 0; db < 4; ++db) {
      int d = db * 16 + l15;
      o[((size_t)b * NSEQ + qrow) * DMODEL + h * 64 + d] = f2bf(oacc[db][r] * inv);
    }
  }
}

extern "C" void kernel_launch(void* const* d_in, const int* in_sizes, int n_in,
                              void* d_out, int out_size, void* d_ws, size_t ws_size,
                              hipStream_t stream) {
  (void)in_sizes; (void)n_in; (void)out_size; (void)ws_size;
  const float* x = (const float*)d_in[0];
  const int* mask = (const int*)d_in[1];
  const float* alibi = (const float*)d_in[2];
  const float* Wq = (const float*)d_in[3];
  const float* Wk = (const float*)d_in[4];
  const float* Wv = (const float*)d_in[5];
  const float* Wo = (const float*)d_in[6];
  float* out = (float*)d_out;

  char* ws = (char*)d_ws;
  const size_t MB = 1u << 20;
  u16* xb  = (u16*)(ws + 0 * MB);    // 16 MB
  u16* wqb = (u16*)(ws + 16 * MB);   // 2 MB
  u16* wkb = (u16*)(ws + 18 * MB);
  u16* wvb = (u16*)(ws + 20 * MB);
  u16* wob = (u16*)(ws + 22 * MB);
  u16* qb  = (u16*)(ws + 24 * MB);   // 16 MB  [B,H,N,64]
  u16* kb  = (u16*)(ws + 40 * MB);   // 16 MB  [B,H,N,64]
  u16* vT  = (u16*)(ws + 56 * MB);   // 16 MB  [B,H,64,N]
  u16* ob  = (u16*)(ws + 72 * MB);   // 16 MB  [B,N,1024]
  u64* mbits = (u64*)(ws + 88 * MB); // 2 MB   [B*N][32]

  cast_f32_bf16<<<8192, 256, 0, stream>>>(x, xb, MTOT * DMODEL);
  cast_f32_bf16<<<1024, 256, 0, stream>>>(Wq, wqb, DMODEL * DMODEL);
  cast_f32_bf16<<<1024, 256, 0, stream>>>(Wk, wkb, DMODEL * DMODEL);
  cast_f32_bf16<<<1024, 256, 0, stream>>>(Wv, wvb, DMODEL * DMODEL);
  cast_f32_bf16<<<1024, 256, 0, stream>>>(Wo, wob, DMODEL * DMODEL);
  pack_mask<<<2048, 256, 0, stream>>>(mask, mbits);

  dim3 gg(64, 8), blk(256);
  gemm_bt<0><<<gg, blk, 0, stream>>>(xb, wqb, qb);
  gemm_bt<0><<<gg, blk, 0, stream>>>(xb, wkb, kb);
  gemm_bt<2><<<gg, blk, 0, stream>>>(xb, wvb, vT);

  attn_kernel<<<2048, blk, 0, stream>>>(qb, kb, vT, alibi, mbits, ob);

  gemm_bt<1><<<gg, blk, 0, stream>>>(ob, wob, out);
}

// Round 3
// 384.733 us; speedup vs baseline: 1.2036x; 1.2036x over previous
//
#include <hip/hip_runtime.h>

#define NSEQ 2048
#define DMODEL 1024
#define NHEAD 16
#define HDIM 64
#define NBATCH 4
#define MTOT 8192
#define ATT_SCALE 0.125f
#define LOG2E 1.4426950408889634f

typedef __bf16 bf16x8 __attribute__((ext_vector_type(8)));
typedef __bf16 bf16x4 __attribute__((ext_vector_type(4)));
typedef float f32x4 __attribute__((ext_vector_type(4)));
typedef unsigned int u32x4 __attribute__((ext_vector_type(4)));
typedef unsigned short u16;
typedef unsigned int u32;
typedef unsigned long long u64;

__device__ __forceinline__ u16 f2bf(float f) {
  u32 u = __builtin_bit_cast(u32, f);
  return (u16)((u + 0x7fffu + ((u >> 16) & 1u)) >> 16);
}

__device__ __forceinline__ void gload_lds16(const void* g, void* l) {
  __builtin_amdgcn_global_load_lds(
      (__attribute__((address_space(1))) const u32*)g,
      (__attribute__((address_space(3))) u32*)l, 16, 0, 0);
}

// ---------------- cast fp32 -> bf16 ----------------
__global__ __launch_bounds__(256) void cast_f32_bf16(const float* __restrict__ in,
                                                     u16* __restrict__ out, int n) {
  int i = (blockIdx.x * 256 + threadIdx.x) * 4;
  if (i >= n) return;
  float4 v = *(const float4*)(in + i);
  ushort4 o;
  o.x = f2bf(v.x); o.y = f2bf(v.y); o.z = f2bf(v.z); o.w = f2bf(v.w);
  *(ushort4*)(out + i) = o;
}

// ---------------- pack mask int32 -> bit per element ----------------
__global__ __launch_bounds__(256) void pack_mask(const int* __restrict__ mask,
                                                 u64* __restrict__ bits) {
  int wave = (blockIdx.x * 256 + threadIdx.x) >> 6;
  int lane = threadIdx.x & 63;
  const int* row = mask + (size_t)wave * NSEQ;
  u64* out = bits + (size_t)wave * 32;
  for (int c = 0; c < 32; ++c) {
    int v = row[c * 64 + lane];
    u64 bl = __ballot(v != 0);
    if (lane == 0) out[c] = bl;
  }
}

// ---------------- BT-GEMM: C[m,n] = sum_k A[m,k]*W[n,k] ----------------
template <int MODE>
__global__ __launch_bounds__(256) void gemm_bt(const u16* __restrict__ A,
                                               const u16* __restrict__ W,
                                               void* __restrict__ C) {
  __shared__ __align__(16) u16 Al[128 * 64];
  __shared__ __align__(16) u16 Bl[128 * 64];
  const int tid = threadIdx.x;
  const int w = tid >> 6, l = tid & 63;
  const int l15 = l & 15, l4 = l >> 4;
  const int bm = blockIdx.x, bn = blockIdx.y;
  const int wm = w >> 1, wn = w & 1;

  f32x4 acc[4][4] = {};

  for (int ks = 0; ks < 1024; ks += 64) {
    __syncthreads();
#pragma unroll
    for (int c = 0; c < 4; ++c) {
      int g = w * 256 + c * 64 + l;
      int row = g >> 3, gc = g & 7;
      int sgc = gc ^ (row & 7);
      gload_lds16(A + (size_t)(bm * 128 + row) * 1024 + ks + sgc * 8, &Al[g * 8]);
      gload_lds16(W + (size_t)(bn * 128 + row) * 1024 + ks + sgc * 8, &Bl[g * 8]);
    }
    __syncthreads();
#pragma unroll
    for (int kc = 0; kc < 2; ++kc) {
      bf16x8 af[4], bfr[4];
#pragma unroll
      for (int mi = 0; mi < 4; ++mi) {
        int row = wm * 64 + mi * 16 + l15;
        int gc2 = (kc * 4 + l4) ^ (row & 7);
        af[mi] = *(const bf16x8*)&Al[row * 64 + gc2 * 8];
      }
#pragma unroll
      for (int ni = 0; ni < 4; ++ni) {
        int row = wn * 64 + ni * 16 + l15;
        int gc2 = (kc * 4 + l4) ^ (row & 7);
        bfr[ni] = *(const bf16x8*)&Bl[row * 64 + gc2 * 8];
      }
#pragma unroll
      for (int mi = 0; mi < 4; ++mi)
#pragma unroll
        for (int ni = 0; ni < 4; ++ni)
          acc[mi][ni] = __builtin_amdgcn_mfma_f32_16x16x32_bf16(af[mi], bfr[ni],
                                                                acc[mi][ni], 0, 0, 0);
    }
  }

#pragma unroll
  for (int mi = 0; mi < 4; ++mi)
#pragma unroll
    for (int ni = 0; ni < 4; ++ni)
#pragma unroll
      for (int r = 0; r < 4; ++r) {
        int m = bm * 128 + wm * 64 + mi * 16 + l4 * 4 + r;
        int n = bn * 128 + wn * 64 + ni * 16 + l15;
        float val = acc[mi][ni][r];
        if constexpr (MODE == 0) {
          int b = m >> 11, row = m & 2047, h = n >> 6, d = n & 63;
          ((u16*)C)[(((size_t)(b * 16 + h)) * NSEQ + row) * 64 + d] = f2bf(val);
        } else if constexpr (MODE == 1) {
          ((float*)C)[(size_t)m * 1024 + n] = val;
        } else {
          int b = m >> 11, kk = m & 2047, h = n >> 6, d = n & 63;
          ((u16*)C)[(((size_t)(b * 16 + h)) * 64 + d) * NSEQ + kk] = f2bf(val);
        }
      }
}

// ---------------- flash attention (swapped-QK^T, register softmax) ----------------
// grid 2048 (XCD-remapped), 4 waves x 16 q-rows. Lane owns q = wq0 + (l&15);
// k spread over (l>>4, reg). P stays in registers (cvt_pk), V read as ds_read_b64
// pairs with matching k-slot permutation. LDS = K/V dbuf only (32 KB).
__global__ __launch_bounds__(256, 4) void attn_kernel(
    const u16* __restrict__ q, const u16* __restrict__ k, const u16* __restrict__ vT,
    const float* __restrict__ alibi, const u64* __restrict__ mbits,
    u16* __restrict__ o) {
  __shared__ __align__(16) u16 Kl[2][64 * 64];
  __shared__ __align__(16) u16 Vl[2][64 * 64];

  const int tid = threadIdx.x, w = tid >> 6, l = tid & 63;
  const int l15 = l & 15, l4 = l >> 4;
  const int W = blockIdx.x;
  const int W2 = (W & 7) * 256 + (W >> 3);
  const int qb = W2 & 31, Y = W2 >> 5;
  const int h = Y >> 2, b = Y & 3, bh = b * 16 + h;
  const int wq0 = qb * 64 + w * 16;
  const int myq = wq0 + l15;

  // Q fragment (rows = l15)
  bf16x8 aq[2];
  {
    const u16* qrow = q + ((size_t)bh * NSEQ + myq) * 64;
    aq[0] = *(const bf16x8*)(qrow + l4 * 8);
    aq[1] = *(const bf16x8*)(qrow + 32 + l4 * 8);
  }

  // staging pointers
  const u16* kg[2]; const u16* vg[2];
#pragma unroll
  for (int c = 0; c < 2; ++c) {
    int g = w * 128 + c * 64 + l;
    int row = g >> 3, gc = g & 7, sgc = gc ^ (row & 7);
    kg[c] = k + ((size_t)bh * NSEQ + row) * 64 + sgc * 8;
    vg[c] = vT + ((size_t)bh * 64 + row) * NSEQ + sgc * 8;
  }

  // per-lane alibi / mask pointers (q fixed = myq)
  const float* alp = alibi + (size_t)h * NSEQ * NSEQ + (size_t)myq * NSEQ + l4 * 4;
  const u64* mrp = mbits + ((size_t)b * NSEQ + myq) * 32;

  // LDS read offsets
  const int kfr[2] = { l15 * 128 + (((0 + l4) ^ (l15 & 7)) << 4),
                       l15 * 128 + (((4 + l4) ^ (l15 & 7)) << 4) };
  int voff[2][2];
#pragma unroll
  for (int c = 0; c < 2; ++c)
#pragma unroll
    for (int jh = 0; jh < 2; ++jh)
      voff[c][jh] = l15 * 128 + (((c * 4 + jh * 2 + (l4 >> 1)) ^ (l15 & 7)) << 4) +
                    (l4 & 1) * 8;

  f32x4 oacc[4] = {};          // q = wq0 + l4*4 + r, d = db*16 + l15
  float m_run = -3.0e38f, l_run = 0.f;

  auto stage = [&](u16* KB, u16* VB) {
#pragma unroll
    for (int c = 0; c < 2; ++c) {
      gload_lds16(kg[c], (char*)KB + (w * 128 + c * 64 + l) * 16);
      kg[c] += 4096;
      gload_lds16(vg[c], (char*)VB + (w * 128 + c * 64 + l) * 16);
      vg[c] += 64;
    }
  };

  stage(Kl[0], Vl[0]);
  __syncthreads();

  auto body = [&](const u16* KB, const u16* VB, u16* KN, u16* VN, int t, bool dost) {
    // per-lane bias/mask loads (issue first, consumed mid-body)
    float4 al[4];
#pragma unroll
    for (int kb = 0; kb < 4; ++kb)
      al[kb] = *(const float4*)(alp + t * 64 + kb * 16);
    u64 mb = mrp[t];
    if (dost) stage(KN, VN);

    // S^T = K Q^T : lane gets q=l15, k = kb*16 + l4*4 + r
    f32x4 st[4];
#pragma unroll
    for (int kb = 0; kb < 4; ++kb) {
      f32x4 z = {0.f, 0.f, 0.f, 0.f};
      st[kb] = z;
#pragma unroll
      for (int kc = 0; kc < 2; ++kc) {
        bf16x8 bk = *(const bf16x8*)((const char*)KB + kfr[kc] + kb * 2048);
        st[kb] = __builtin_amdgcn_mfma_f32_16x16x32_bf16(bk, aq[kc], st[kb], 0, 0, 0);
      }
    }

    // scale + alibi (+ mask, all-ones fast path)
#pragma unroll
    for (int kb = 0; kb < 4; ++kb)
#pragma unroll
      for (int r = 0; r < 4; ++r)
        st[kb][r] = fmaf(st[kb][r], ATT_SCALE, al[kb][r]);
    if (!__all(mb == ~0ull)) {
#pragma unroll
      for (int kb = 0; kb < 4; ++kb)
#pragma unroll
        for (int r = 0; r < 4; ++r)
          if (!((mb >> (kb * 16 + l4 * 4 + r)) & 1)) st[kb][r] = -3.0e38f;
    }

    // row max: in-lane tree (16) + xor16 + xor32
    float m0 = fmaxf(fmaxf(st[0][0], st[0][1]), fmaxf(st[0][2], st[0][3]));
    float m1 = fmaxf(fmaxf(st[1][0], st[1][1]), fmaxf(st[1][2], st[1][3]));
    float m2 = fmaxf(fmaxf(st[2][0], st[2][1]), fmaxf(st[2][2], st[2][3]));
    float m3 = fmaxf(fmaxf(st[3][0], st[3][1]), fmaxf(st[3][2], st[3][3]));
    float tm = fmaxf(fmaxf(m0, m1), fmaxf(m2, m3));
    tm = fmaxf(tm, __shfl_xor(tm, 16));
    tm = fmaxf(tm, __shfl_xor(tm, 32));

    // defer-max rescale
    if (__any(tm > m_run + 4.0f)) {
      float mn = fmaxf(m_run, tm);
      float fac = exp2f((m_run - mn) * LOG2E);
      l_run *= fac;
      m_run = mn;
#pragma unroll
      for (int r = 0; r < 4; ++r) {
        float fr = __shfl(fac, l4 * 4 + r);
#pragma unroll
        for (int db = 0; db < 4; ++db) oacc[db][r] *= fr;
      }
    }

    // exp + sum
    float negm = -m_run * LOG2E;
    float p[16];
#pragma unroll
    for (int kb = 0; kb < 4; ++kb)
#pragma unroll
      for (int r = 0; r < 4; ++r)
        p[kb * 4 + r] = exp2f(fmaf(st[kb][r], LOG2E, negm));
    float s0 = (p[0] + p[1]) + (p[2] + p[3]);
    float s1 = (p[4] + p[5]) + (p[6] + p[7]);
    float s2 = (p[8] + p[9]) + (p[10] + p[11]);
    float s3 = (p[12] + p[13]) + (p[14] + p[15]);
    float ts = (s0 + s1) + (s2 + s3);
    ts += __shfl_xor(ts, 16);
    ts += __shfl_xor(ts, 32);
    l_run += ts;

    // pack P to bf16 pairs (in registers; no LDS)
    u32 Wp[8];
#pragma unroll
    for (int i = 0; i < 8; ++i)
      asm("v_cvt_pk_bf16_f32 %0, %1, %2" : "=v"(Wp[i]) : "v"(p[2 * i]), "v"(p[2 * i + 1]));

    // O += P V  (k-slot order: slot(l4,j) = c*32 + (j>>2)*16 + l4*4 + (j&3))
#pragma unroll
    for (int c = 0; c < 2; ++c) {
      u32x4 wv = {Wp[4 * c], Wp[4 * c + 1], Wp[4 * c + 2], Wp[4 * c + 3]};
      bf16x8 pa = __builtin_bit_cast(bf16x8, wv);
#pragma unroll
      for (int db = 0; db < 4; ++db) {
        bf16x4 v0 = *(const bf16x4*)((const char*)VB + voff[c][0] + db * 2048);
        bf16x4 v1 = *(const bf16x4*)((const char*)VB + voff[c][1] + db * 2048);
        bf16x8 bv = __builtin_shufflevector(v0, v1, 0, 1, 2, 3, 4, 5, 6, 7);
        oacc[db] = __builtin_amdgcn_mfma_f32_16x16x32_bf16(pa, bv, oacc[db], 0, 0, 0);
      }
    }
    __syncthreads();
  };

  for (int t2 = 0; t2 < 16; ++t2) {
    body(Kl[0], Vl[0], Kl[1], Vl[1], t2 * 2, true);
    body(Kl[1], Vl[1], Kl[0], Vl[0], t2 * 2 + 1, t2 < 15);
  }

  // normalize + write O (q = wq0 + l4*4 + r, d = db*16 + l15)
#pragma unroll
  for (int r = 0; r < 4; ++r) {
    float lr = __shfl(l_run, l4 * 4 + r);
    float inv = __builtin_amdgcn_rcpf(lr);
    int qq = wq0 + l4 * 4 + r;
#pragma unroll
    for (int db = 0; db < 4; ++db) {
      int d = db * 16 + l15;
      o[((size_t)b * NSEQ + qq) * DMODEL + h * 64 + d] = f2bf(oacc[db][r] * inv);
    }
  }
}

extern "C" void kernel_launch(void* const* d_in, const int* in_sizes, int n_in,
                              void* d_out, int out_size, void* d_ws, size_t ws_size,
                              hipStream_t stream) {
  (void)in_sizes; (void)n_in; (void)out_size; (void)ws_size;
  const float* x = (const float*)d_in[0];
  const int* mask = (const int*)d_in[1];
  const float* alibi = (const float*)d_in[2];
  const float* Wq = (const float*)d_in[3];
  const float* Wk = (const float*)d_in[4];
  const float* Wv = (const float*)d_in[5];
  const float* Wo = (const float*)d_in[6];
  float* out = (float*)d_out;

  char* ws = (char*)d_ws;
  const size_t MB = 1u << 20;
  u16* xb  = (u16*)(ws + 0 * MB);    // 16 MB
  u16* wqb = (u16*)(ws + 16 * MB);   // 2 MB
  u16* wkb = (u16*)(ws + 18 * MB);
  u16* wvb = (u16*)(ws + 20 * MB);
  u16* wob = (u16*)(ws + 22 * MB);
  u16* qb  = (u16*)(ws + 24 * MB);   // 16 MB  [B,H,N,64]
  u16* kb  = (u16*)(ws + 40 * MB);   // 16 MB  [B,H,N,64]
  u16* vT  = (u16*)(ws + 56 * MB);   // 16 MB  [B,H,64,N]
  u16* ob  = (u16*)(ws + 72 * MB);   // 16 MB  [B,N,1024]
  u64* mbits = (u64*)(ws + 88 * MB); // 2 MB   [B*N][32]

  cast_f32_bf16<<<8192, 256, 0, stream>>>(x, xb, MTOT * DMODEL);
  cast_f32_bf16<<<1024, 256, 0, stream>>>(Wq, wqb, DMODEL * DMODEL);
  cast_f32_bf16<<<1024, 256, 0, stream>>>(Wk, wkb, DMODEL * DMODEL);
  cast_f32_bf16<<<1024, 256, 0, stream>>>(Wv, wvb, DMODEL * DMODEL);
  cast_f32_bf16<<<1024, 256, 0, stream>>>(Wo, wob, DMODEL * DMODEL);
  pack_mask<<<2048, 256, 0, stream>>>(mask, mbits);

  dim3 gg(64, 8), blk(256);
  gemm_bt<0><<<gg, blk, 0, stream>>>(xb, wqb, qb);
  gemm_bt<0><<<gg, blk, 0, stream>>>(xb, wkb, kb);
  gemm_bt<2><<<gg, blk, 0, stream>>>(xb, wvb, vT);

  attn_kernel<<<2048, blk, 0, stream>>>(qb, kb, vT, alibi, mbits, ob);

  gemm_bt<1><<<gg, blk, 0, stream>>>(ob, wob, out);
}